// Round 9
// baseline (293.184 us; speedup 1.0000x reference)
//
#include <hip/hip_runtime.h>

// VectorQuantizer forward: inputs [64,2048,64] f32, codebook [1024,64] f32.
// Outputs (f32, concat): quantized_ste [8388608], loss [1], indices-as-float [131072].
//
// Round 9: round-8 confirmed the binding resource is LDS lane-delivered bytes
// at 85 B/cyc/CU (predicted 246 us, observed 250). Cut delivered-per-FMA from
// 1.5 B (8x4 tile) to 1.0 B (8x8 tile), and halve A re-reads with N=256 tiles
// (NTILES=4). DS: 394K cyc/CU = 164 us; VALU ~140 us -> near-balanced.
// LDS is hand-packed into one 80 KB buffer (sA 16K + sB 64K, side arrays
// unioned into dead phases) so exactly 2 blocks/CU fit.
//
// Numerics: bit-identical to round 8 (absmax 0.0): same A-norm 16-dim partial
// chains, same sequential k=0..63 dot chain, d2 = fl(fl(A-2dot)+csq), u64-key
// (d2_bits<<32|idx) min = first-index-wins, order-free.

#define NROWS  131072
#define DIM    64
#define KCB    1024
#define MT     64             // rows per block
#define NT     256            // codes per LDS tile
#define NTILES (KCB / NT)     // 4
#define QSIZE  (NROWS * DIM)  // 8388608

__global__ __launch_bounds__(256) void vq_prep(const float* __restrict__ cb,
                                               float* __restrict__ csq,
                                               float* __restrict__ loss_slot) {
    int k = blockIdx.x * 256 + threadIdx.x;
    if (k < KCB) {
        const float* c = cb + k * DIM;
        float a0 = 0.f, a1 = 0.f, a2 = 0.f, a3 = 0.f;
        #pragma unroll
        for (int d = 0; d < 16; ++d) {
            a0 = fmaf(c[d],      c[d],      a0);
            a1 = fmaf(c[16 + d], c[16 + d], a1);
            a2 = fmaf(c[32 + d], c[32 + d], a2);
            a3 = fmaf(c[48 + d], c[48 + d], a3);
        }
        csq[k] = (a0 + a1) + (a2 + a3);
    }
    if (blockIdx.x == 0 && threadIdx.x == 0) *loss_slot = 0.f;  // zero loss accumulator every call
}

__global__ __launch_bounds__(256, 2) void vq_main(const float* __restrict__ x,
                                                  const float* __restrict__ cb,
                                                  const float* __restrict__ csq,
                                                  float* __restrict__ out_q,
                                                  float* __restrict__ out_loss,
                                                  float* __restrict__ out_idx) {
    // Hand-packed LDS: exactly 80 KB so 2 blocks/CU fit (160 KB / CU).
    //   [0      .. 65536)  sB[64][256]  dim-major B tile   (alias: sPart, sFinal, sLoss)
    //   [65536  .. 81920)  sA[64][64]   dim-major A tile   (alias: sWK)
    __shared__ __align__(16) char smem[81920];
    float (*sB)[NT]  = reinterpret_cast<float (*)[NT]>(smem);
    float (*sA)[MT]  = reinterpret_cast<float (*)[MT]>(smem + 65536);
    float (*sPart)[4] = reinterpret_cast<float (*)[4]>(smem);            // pre-tile-0 only
    unsigned long long (*sWK)[MT] =
        reinterpret_cast<unsigned long long (*)[MT]>(smem + 65536);      // post-k-loop only
    int*   sFinal = reinterpret_cast<int*>(smem + 4096);                 // post-k-loop only
    float* sLoss  = reinterpret_cast<float*>(smem + 8192);               // epilogue only

    const int tid  = threadIdx.x;
    const int lane = tid & 63;
    const int wid  = tid >> 6;
    const int mg   = tid & 7;        // row group: rows 8*mg .. 8*mg+7
    const int ng   = tid >> 3;       // code group: codes 8*ng .. 8*ng+7 of tile
    const size_t rowbase = (size_t)blockIdx.x * MT;

    // ---- stage A dim-major + exact A-norm 16-dim partial chains ----
    {
        const int r = tid >> 2;      // 0..63
        const int q = tid & 3;       // dim quarter 16q..16q+15
        const float4* gx = reinterpret_cast<const float4*>(
            x + (rowbase + (size_t)r) * DIM + 16 * q);
        float4 v0 = gx[0], v1 = gx[1], v2 = gx[2], v3 = gx[3];
        float t[16] = {v0.x, v0.y, v0.z, v0.w, v1.x, v1.y, v1.z, v1.w,
                       v2.x, v2.y, v2.z, v2.w, v3.x, v3.y, v3.z, v3.w};
        float aq = 0.f;
        #pragma unroll
        for (int j = 0; j < 16; ++j) aq = fmaf(t[j], t[j], aq);  // exact chain q
        sPart[r][q] = aq;
        #pragma unroll
        for (int j = 0; j < 16; ++j) sA[16 * q + j][r] = t[j];   // dim-major scatter
    }
    __syncthreads();

    // each thread sums its 8 rows' norms directly (exact (p0+p1)+(p2+p3) chain)
    float asq[8];
    #pragma unroll
    for (int i = 0; i < 8; ++i) {
        const int r = 8 * mg + i;
        asq[i] = (sPart[r][0] + sPart[r][1]) + (sPart[r][2] + sPart[r][3]);
    }

    unsigned long long key[8];
    #pragma unroll
    for (int i = 0; i < 8; ++i) key[i] = ~0ull;

    // ---- N-tile loop ----
    for (int t = 0; t < NTILES; ++t) {
        __syncthreads();   // previous tile's readers done (also fences sPart before tile 0)
        // stage B tile dim-major: 256 codes x 64 dims; 2 passes of (code=tid>>1, half=tid&1)
        #pragma unroll
        for (int p = 0; p < 2; ++p) {
            const int n = (tid >> 1) + 128 * p;
            const int h = tid & 1;
            const float4* gc = reinterpret_cast<const float4*>(
                cb + ((size_t)(t * NT + n)) * DIM + 32 * h);
            float4 u[8];
            #pragma unroll
            for (int j = 0; j < 8; ++j) u[j] = gc[j];
            #pragma unroll
            for (int j = 0; j < 8; ++j) {
                sB[32 * h + 4 * j + 0][n] = u[j].x;
                sB[32 * h + 4 * j + 1][n] = u[j].y;
                sB[32 * h + 4 * j + 2][n] = u[j].z;
                sB[32 * h + 4 * j + 3][n] = u[j].w;
            }
        }
        __syncthreads();

        float acc[8][8];
        #pragma unroll
        for (int i = 0; i < 8; ++i)
            #pragma unroll
            for (int j = 0; j < 8; ++j) acc[i][j] = 0.f;

        #pragma unroll 4
        for (int k = 0; k < DIM; ++k) {
            const float4 a0 = *reinterpret_cast<const float4*>(&sA[k][8 * mg]);
            const float4 a1 = *reinterpret_cast<const float4*>(&sA[k][8 * mg + 4]);
            const float4 b0 = *reinterpret_cast<const float4*>(&sB[k][8 * ng]);
            const float4 b1 = *reinterpret_cast<const float4*>(&sB[k][8 * ng + 4]);
            const float a[8] = {a0.x, a0.y, a0.z, a0.w, a1.x, a1.y, a1.z, a1.w};
            const float b[8] = {b0.x, b0.y, b0.z, b0.w, b1.x, b1.y, b1.z, b1.w};
            #pragma unroll
            for (int i = 0; i < 8; ++i)
                #pragma unroll
                for (int j = 0; j < 8; ++j)
                    acc[i][j] = fmaf(a[i], b[j], acc[i][j]);
        }

        // ---- tail: d2 + u64-key update (ref expression roundings preserved) ----
        const float4 cs0 = *reinterpret_cast<const float4*>(csq + t * NT + 8 * ng);
        const float4 cs1 = *reinterpret_cast<const float4*>(csq + t * NT + 8 * ng + 4);
        const float cs[8] = {cs0.x, cs0.y, cs0.z, cs0.w, cs1.x, cs1.y, cs1.z, cs1.w};
        #pragma unroll
        for (int j = 0; j < 8; ++j) {
            const int n = t * NT + 8 * ng + j;
            #pragma unroll
            for (int i = 0; i < 8; ++i) {
                const float tt = asq[i] - 2.0f * acc[i][j];  // one rounding (2*acc exact)
                const float dd = tt + cs[j];                 // second rounding
                const unsigned long long kk =
                    ((unsigned long long)__float_as_uint(dd) << 32) | (unsigned)n;
                key[i] = kk < key[i] ? kk : key[i];
            }
        }
    }

    // ---- cross-lane argmin (u64 keys, order-free, first-index-wins) ----
    #pragma unroll
    for (int i = 0; i < 8; ++i) {
        unsigned long long kk = key[i];
        #pragma unroll
        for (int m = 8; m <= 32; m <<= 1) {
            unsigned long long o = __shfl_xor(kk, m, 64);
            kk = o < kk ? o : kk;
        }
        key[i] = kk;
    }
    __syncthreads();   // all k-loops done: sA region may now be reused as sWK
    if (lane < 8) {
        #pragma unroll
        for (int i = 0; i < 8; ++i) sWK[wid][8 * lane + i] = key[i];
    }
    __syncthreads();
    if (tid < MT) {
        unsigned long long b0 = sWK[0][tid], b1 = sWK[1][tid];
        unsigned long long b2 = sWK[2][tid], b3 = sWK[3][tid];
        unsigned long long m01 = b0 < b1 ? b0 : b1;
        unsigned long long m23 = b2 < b3 ? b2 : b3;
        unsigned long long fk  = m01 < m23 ? m01 : m23;
        const int idx = (int)(unsigned)fk;
        sFinal[tid] = idx;
        out_idx[rowbase + tid] = (float)idx;
    }
    __syncthreads();

    // ---- epilogue: coalesced STE write + loss partial ----
    const size_t base = rowbase * DIM;
    float lsum = 0.f;
    #pragma unroll 4
    for (int i = tid; i < MT * DIM; i += 256) {
        const int r = i >> 6;
        const int d = i & 63;
        const int kb = sFinal[r];            // wave-uniform per iteration
        const float q  = cb[(size_t)kb * DIM + d];
        const float xe = x[base + i];
        out_q[base + i] = xe + (q - xe);     // STE forward, ref's rounding
        const float df = q - xe;
        lsum = fmaf(df, df, lsum);
    }
    #pragma unroll
    for (int off = 32; off; off >>= 1) lsum += __shfl_down(lsum, off, 64);
    if (lane == 0) sLoss[wid] = lsum;
    __syncthreads();
    if (tid == 0) {
        const float tot = (sLoss[0] + sLoss[1]) + (sLoss[2] + sLoss[3]);
        atomicAdd(out_loss, tot * (1.25f / 8388608.0f));  // (q + 0.25*e) / count
    }
}

extern "C" void kernel_launch(void* const* d_in, const int* in_sizes, int n_in,
                              void* d_out, int out_size, void* d_ws, size_t ws_size,
                              hipStream_t stream) {
    const float* x  = (const float*)d_in[0];   // 8388608
    const float* cb = (const float*)d_in[1];   // 65536
    float* out      = (float*)d_out;
    float* out_loss = out + QSIZE;             // [8388608]
    float* out_idx  = out + QSIZE + 1;         // [8388609 .. 8519680]
    float* csq      = (float*)d_ws;            // 1024 floats scratch

    vq_prep<<<4, 256, 0, stream>>>(cb, csq, out_loss);
    vq_main<<<NROWS / MT, 256, 0, stream>>>(x, cb, csq, out, out_loss, out_idx);
}